// Round 11
// baseline (357.212 us; speedup 1.0000x reference)
//
#include <hip/hip_runtime.h>
#include <hip/hip_bf16.h>

typedef unsigned short u16;
typedef __attribute__((ext_vector_type(8))) short bf16x8;
typedef __attribute__((ext_vector_type(8))) unsigned short u16x8;
typedef __attribute__((ext_vector_type(4))) float f32x4;

#define NBT 64
#define SEQ 197
#define CDIM 768
#define NH 12
#define HD 64
#define MVALID (NBT * SEQ)       // 12608
#define MPAD 12800               // 50 * 256 (also 100 * 128)
#define HADP 192
#define HPAD 256
#define QKVSZ (NBT * NH * SEQ * HD)  // 9682944 elements

__device__ __forceinline__ u16 f2b(float f) {
    __hip_bfloat16 h = __float2bfloat16(f);
    return __builtin_bit_cast(u16, h);
}

#define GLL16(gp, lp) __builtin_amdgcn_global_load_lds( \
    (__attribute__((address_space(1))) void*)(gp),      \
    (__attribute__((address_space(3))) void*)(lp), 16, 0, 0)

// ---------------------------------------------------------------- cast x -> bf16, pad rows to MPAD with zeros
__global__ __launch_bounds__(256) void cast_x_kernel(const float* __restrict__ x, u16* __restrict__ xb) {
    long i = ((long)blockIdx.x * 256 + threadIdx.x) * 8;
    u16x8 r;
    if (i < (long)MVALID * CDIM) {
        const float4* p = (const float4*)(x + i);
        float4 a = p[0], b = p[1];
        r[0] = f2b(a.x); r[1] = f2b(a.y); r[2] = f2b(a.z); r[3] = f2b(a.w);
        r[4] = f2b(b.x); r[5] = f2b(b.y); r[6] = f2b(b.z); r[7] = f2b(b.w);
    } else {
#pragma unroll
        for (int j = 0; j < 8; ++j) r[j] = 0;
    }
    *(u16x8*)(xb + i) = r;
}

// ---------------------------------------------------------------- fp32 [K][N] -> bf16 [NP][KP] transpose+cast, zero pad
__global__ __launch_bounds__(256) void transpose_cast_kernel(
    const float* __restrict__ in, u16* __restrict__ out, int K, int N, int KP) {
    __shared__ float tile[64][65];
    int k0 = blockIdx.x * 64;
    int n0 = blockIdx.y * 64;
    int c  = threadIdx.x & 63;
    int r0 = threadIdx.x >> 6;
#pragma unroll
    for (int rr = r0; rr < 64; rr += 4) {
        int k = k0 + rr, n = n0 + c;
        tile[rr][c] = (k < K && n < N) ? in[(long)k * N + n] : 0.f;
    }
    __syncthreads();
#pragma unroll
    for (int rr = r0; rr < 64; rr += 4) {
        out[(long)(n0 + rr) * KP + k0 + c] = f2b(tile[c][rr]);
    }
}

// ---------------------------------------------------------------- epilogue dispatch (shared by both GEMMs)
template <int MODE>
__device__ __forceinline__ void epi_store(long m, long n, float v,
    const float* __restrict__ bias, const float* __restrict__ resid,
    u16* __restrict__ ob, float* __restrict__ of) {
    if constexpr (MODE == 0) {
        float bv = (n < HADP) ? bias[n] : 0.f;
        ob[m * HPAD + n] = f2b(v + bv);
    } else if constexpr (MODE == 1) {
        float val = 0.f;
        if (m < MVALID) val = v + bias[n] + resid[m * CDIM + n];
        ob[m * CDIM + n] = f2b(val);
    } else if constexpr (MODE == 2) {
        if (m < MVALID) {
            int mm = (int)m;
            int bb = mm / SEQ;
            int t  = mm - bb * SEQ;
            int nn = (int)n;
            int which = nn / CDIM;
            int c  = nn - which * CDIM;
            int hh = c >> 6, d = c & 63;
            ob[(long)which * QKVSZ + ((long)(bb * NH + hh) * SEQ + t) * HD + d] = f2b(v + bias[nn]);
        }
    } else {
        if (m < MVALID) of[m * CDIM + n] = v + bias[n];
    }
}

// ---------------------------------------------------------------- 128x128 m97-structure GEMM (a1, a2)
template <int MODE, int NB>
__device__ __forceinline__ void gemm_body(
    const u16* __restrict__ A, const u16* __restrict__ Bt,
    const float* __restrict__ bias, const float* __restrict__ resid,
    u16* __restrict__ ob, float* __restrict__ of, int K) {
    __shared__ __align__(16) u16 As[128 * 64];
    __shared__ __align__(16) u16 Bs[128 * 64];
    const int tid  = threadIdx.x;
    const int lane = tid & 63;
    const int w    = tid >> 6;
    const int wm   = w >> 1, wn = w & 1;

    const int nwg  = (int)gridDim.x;
    const int bid  = (int)blockIdx.x;
    const int q    = nwg >> 3, r = nwg & 7;
    const int xcd  = bid & 7;
    const int lid  = bid >> 3;
    const int wgid = (xcd < r ? xcd * (q + 1) : r * (q + 1) + (xcd - r) * q) + lid;
    const long m0  = (long)(wgid / NB) * 128;
    const long n0  = (long)(wgid % NB) * 128;

    const int rA = lane >> 3;
    const int cA = (lane & 7) * 8;

    const u16* ga[4];
    const u16* gb[4];
#pragma unroll
    for (int ii = 0; ii < 4; ++ii) {
        int i = w * 4 + ii;
        ga[ii] = A  + (m0 + i * 8 + rA) * K + cA;
        gb[ii] = Bt + (n0 + i * 8 + rA) * K + cA;
    }

    int aoff[4], boff[4];
#pragma unroll
    for (int t = 0; t < 4; ++t) {
        aoff[t] = (wm * 64 + t * 16 + (lane & 15)) * 64 + (lane >> 4) * 8;
        boff[t] = (wn * 64 + t * 16 + (lane & 15)) * 64 + (lane >> 4) * 8;
    }

    f32x4 acc[4][4] = {};
    const int kSteps = K >> 6;
    for (int kt = 0; kt < kSteps; ++kt) {
#pragma unroll
        for (int ii = 0; ii < 4; ++ii) {
            int i = w * 4 + ii;
            GLL16(ga[ii] + kt * 64, &As[i * 512]);
            GLL16(gb[ii] + kt * 64, &Bs[i * 512]);
        }
        __syncthreads();
#pragma unroll
        for (int kc = 0; kc < 2; ++kc) {
            bf16x8 af[4], bg[4];
#pragma unroll
            for (int t = 0; t < 4; ++t) af[t] = *(const bf16x8*)&As[aoff[t] + kc * 32];
#pragma unroll
            for (int t = 0; t < 4; ++t) bg[t] = *(const bf16x8*)&Bs[boff[t] + kc * 32];
#pragma unroll
            for (int mi = 0; mi < 4; ++mi)
#pragma unroll
                for (int ni = 0; ni < 4; ++ni)
                    acc[mi][ni] = __builtin_amdgcn_mfma_f32_16x16x32_bf16(af[mi], bg[ni], acc[mi][ni], 0, 0, 0);
        }
        __syncthreads();
    }

    const int rb = (lane >> 4) * 4;
    const int cl = lane & 15;
#pragma unroll
    for (int mi = 0; mi < 4; ++mi)
#pragma unroll
        for (int rr = 0; rr < 4; ++rr) {
            long m = m0 + wm * 64 + mi * 16 + rb + rr;
#pragma unroll
            for (int ni = 0; ni < 4; ++ni)
                epi_store<MODE>(m, n0 + wn * 64 + ni * 16 + cl, acc[mi][ni][rr], bias, resid, ob, of);
        }
}

__global__ __launch_bounds__(256, 4) void gemm_a1(
    const u16* __restrict__ A, const u16* __restrict__ Bt, const float* __restrict__ bias,
    u16* __restrict__ ob, int K) {
    gemm_body<0, 2>(A, Bt, bias, nullptr, ob, nullptr, K);
}
__global__ __launch_bounds__(256, 4) void gemm_a2(
    const u16* __restrict__ A, const u16* __restrict__ Bt, const float* __restrict__ bias,
    const float* __restrict__ resid, u16* __restrict__ ob, int K) {
    gemm_body<1, 6>(A, Bt, bias, resid, ob, nullptr, K);
}

// ---------------------------------------------------------------- 256x256 8-phase GEMM (T2+T3+T4+T5)
// BK=32, 4-slot LDS ring (4 x 16KB A + 4 x 16KB B = 128KB), 8 waves (2M x 4N),
// per-wave C = 128x64 = acc[8][4]. Per K-tile: 2 phases x {ds_read || 2xGLL(j+2)
// -> s_barrier -> lgkmcnt(0)+sched_barrier -> setprio(1) 16 MFMA setprio(0) -> barrier},
// counted vmcnt(4) once per tile (never 0 mid-loop; drains 4->0 in epilogue).
// T2 swizzle (involution, rule #21): global col-group g stored at LDS physical
// group g ^ (row&3); ds_read fetches ((lane>>4) ^ (lane&3))*8.
// GLL16 LDS dest is the WAVE-UNIFORM chunk base (m104: HW writes base + lane*16).
template <int MODE, int NB, int NT>
__global__ __launch_bounds__(512, 2) void gemm8p(
    const u16* __restrict__ A, const u16* __restrict__ Bt,
    const float* __restrict__ bias,
    u16* __restrict__ ob, float* __restrict__ of, int K) {
    __shared__ __align__(16) u16 As[4][256 * 32];
    __shared__ __align__(16) u16 Bs[4][256 * 32];
    const int tid  = threadIdx.x;
    const int lane = tid & 63;
    const int w    = tid >> 6;      // 0..7
    const int wm   = w >> 2;        // 0..1 -> M half
    const int wn   = w & 3;         // 0..3 -> N quarter

    const int nwg  = (int)gridDim.x;
    const int bid  = (int)blockIdx.x;
    const int q    = nwg >> 3, r = nwg & 7;
    const int xcd  = bid & 7;
    const int lid  = bid >> 3;
    const int wgid = (xcd < r ? xcd * (q + 1) : r * (q + 1) + (xcd - r) * q) + lid;
    const long m0  = (long)(wgid / NB) * 256;
    const long n0  = (long)(wgid % NB) * 256;

    // ---- staging: chunk c covers tile rows [c*16, c*16+16); wave w owns chunks w*2, w*2+1.
    // HW: lane l writes LDS chunkbase + l*16B = row c*16+(l>>2), phys col (l&3)*8.
    // Global source pre-swizzled: row = c*16+(l>>2), col = 8*((l&3) ^ ((l>>2)&3)).
    const int cA    = w * 2;
    const int srow  = lane >> 2;
    const int scol  = 8 * ((lane & 3) ^ ((lane >> 2) & 3));
    const u16* gA0 = A  + (m0 + cA * 16 + srow) * K + scol;
    const u16* gA1 = gA0 + 16 * K;
    const u16* gB0 = Bt + (n0 + cA * 16 + srow) * K + scol;
    const u16* gB1 = gB0 + 16 * K;
    u16* lA = &As[0][cA * 512];   // wave-uniform chunk base (m104)
    u16* lB = &Bs[0][cA * 512];

    // ---- fragment read offsets (u16), swizzled: addr = row*32 + ((l>>4)*8 ^ ((l&3)<<3))
    const int xcol = ((lane >> 4) * 8) ^ ((lane & 3) << 3);
    const int aob  = (wm * 128 + (lane & 15)) * 32 + xcol;
    const int bob  = (wn * 64  + (lane & 15)) * 32 + xcol;

    f32x4 acc[8][4] = {};

    // prologue: stage tiles 0,1 (FIFO: tile0 x4, tile1 x4) -> wait tile0 -> barrier
    GLL16(gA0,          lA);            GLL16(gA1,          lA + 512);
    GLL16(gB0,          lB);            GLL16(gB1,          lB + 512);
    GLL16(gA0 + 32,     lA + 8192);     GLL16(gA1 + 32,     lA + 8192 + 512);
    GLL16(gB0 + 32,     lB + 8192);     GLL16(gB1 + 32,     lB + 8192 + 512);
    asm volatile("s_waitcnt vmcnt(4)" ::: "memory");
    __builtin_amdgcn_s_barrier();

    for (int j = 0; j < NT; ++j) {
        const int sj = j & 3;
        const u16* as = &As[sj][0];
        const u16* bs = &Bs[sj][0];
        const int s2 = (j + 2) & 3;
        const int k2 = (j + 2) * 32;
        bf16x8 af0, af1, af2, af3, bg0, bg1, bg2, bg3;

        // ---------------- phase A: m-frags 0-3
        af0 = *(const bf16x8*)(as + aob);
        af1 = *(const bf16x8*)(as + aob + 512);
        af2 = *(const bf16x8*)(as + aob + 1024);
        af3 = *(const bf16x8*)(as + aob + 1536);
        bg0 = *(const bf16x8*)(bs + bob);
        bg1 = *(const bf16x8*)(bs + bob + 512);
        bg2 = *(const bf16x8*)(bs + bob + 1024);
        bg3 = *(const bf16x8*)(bs + bob + 1536);
        if (j + 2 < NT) {
            GLL16(gA0 + k2, lA + s2 * 8192);
            GLL16(gA1 + k2, lA + s2 * 8192 + 512);
        }
        __builtin_amdgcn_s_barrier();
        asm volatile("s_waitcnt lgkmcnt(0)" ::: "memory");
        __builtin_amdgcn_sched_barrier(0);
        __builtin_amdgcn_s_setprio(1);
        acc[0][0] = __builtin_amdgcn_mfma_f32_16x16x32_bf16(af0, bg0, acc[0][0], 0, 0, 0);
        acc[0][1] = __builtin_amdgcn_mfma_f32_16x16x32_bf16(af0, bg1, acc[0][1], 0, 0, 0);
        acc[0][2] = __builtin_amdgcn_mfma_f32_16x16x32_bf16(af0, bg2, acc[0][2], 0, 0, 0);
        acc[0][3] = __builtin_amdgcn_mfma_f32_16x16x32_bf16(af0, bg3, acc[0][3], 0, 0, 0);
        acc[1][0] = __builtin_amdgcn_mfma_f32_16x16x32_bf16(af1, bg0, acc[1][0], 0, 0, 0);
        acc[1][1] = __builtin_amdgcn_mfma_f32_16x16x32_bf16(af1, bg1, acc[1][1], 0, 0, 0);
        acc[1][2] = __builtin_amdgcn_mfma_f32_16x16x32_bf16(af1, bg2, acc[1][2], 0, 0, 0);
        acc[1][3] = __builtin_amdgcn_mfma_f32_16x16x32_bf16(af1, bg3, acc[1][3], 0, 0, 0);
        acc[2][0] = __builtin_amdgcn_mfma_f32_16x16x32_bf16(af2, bg0, acc[2][0], 0, 0, 0);
        acc[2][1] = __builtin_amdgcn_mfma_f32_16x16x32_bf16(af2, bg1, acc[2][1], 0, 0, 0);
        acc[2][2] = __builtin_amdgcn_mfma_f32_16x16x32_bf16(af2, bg2, acc[2][2], 0, 0, 0);
        acc[2][3] = __builtin_amdgcn_mfma_f32_16x16x32_bf16(af2, bg3, acc[2][3], 0, 0, 0);
        acc[3][0] = __builtin_amdgcn_mfma_f32_16x16x32_bf16(af3, bg0, acc[3][0], 0, 0, 0);
        acc[3][1] = __builtin_amdgcn_mfma_f32_16x16x32_bf16(af3, bg1, acc[3][1], 0, 0, 0);
        acc[3][2] = __builtin_amdgcn_mfma_f32_16x16x32_bf16(af3, bg2, acc[3][2], 0, 0, 0);
        acc[3][3] = __builtin_amdgcn_mfma_f32_16x16x32_bf16(af3, bg3, acc[3][3], 0, 0, 0);
        __builtin_amdgcn_s_setprio(0);
        __builtin_amdgcn_s_barrier();

        // ---------------- phase B: m-frags 4-7 (reuse bg)
        af0 = *(const bf16x8*)(as + aob + 2048);
        af1 = *(const bf16x8*)(as + aob + 2560);
        af2 = *(const bf16x8*)(as + aob + 3072);
        af3 = *(const bf16x8*)(as + aob + 3584);
        if (j + 2 < NT) {
            GLL16(gB0 + k2, lB + s2 * 8192);
            GLL16(gB1 + k2, lB + s2 * 8192 + 512);
        }
        __builtin_amdgcn_s_barrier();
        asm volatile("s_waitcnt lgkmcnt(0)" ::: "memory");
        __builtin_amdgcn_sched_barrier(0);
        __builtin_amdgcn_s_setprio(1);
        acc[4][0] = __builtin_amdgcn_mfma_f32_16x16x32_bf16(af0, bg0, acc[4][0], 0, 0, 0);
        acc[4][1] = __builtin_amdgcn_mfma_f32_16x16x32_bf16(af0, bg1, acc[4][1], 0, 0, 0);
        acc[4][2] = __builtin_amdgcn_mfma_f32_16x16x32_bf16(af0, bg2, acc[4][2], 0, 0, 0);
        acc[4][3] = __builtin_amdgcn_mfma_f32_16x16x32_bf16(af0, bg3, acc[4][3], 0, 0, 0);
        acc[5][0] = __builtin_amdgcn_mfma_f32_16x16x32_bf16(af1, bg0, acc[5][0], 0, 0, 0);
        acc[5][1] = __builtin_amdgcn_mfma_f32_16x16x32_bf16(af1, bg1, acc[5][1], 0, 0, 0);
        acc[5][2] = __builtin_amdgcn_mfma_f32_16x16x32_bf16(af1, bg2, acc[5][2], 0, 0, 0);
        acc[5][3] = __builtin_amdgcn_mfma_f32_16x16x32_bf16(af1, bg3, acc[5][3], 0, 0, 0);
        acc[6][0] = __builtin_amdgcn_mfma_f32_16x16x32_bf16(af2, bg0, acc[6][0], 0, 0, 0);
        acc[6][1] = __builtin_amdgcn_mfma_f32_16x16x32_bf16(af2, bg1, acc[6][1], 0, 0, 0);
        acc[6][2] = __builtin_amdgcn_mfma_f32_16x16x32_bf16(af2, bg2, acc[6][2], 0, 0, 0);
        acc[6][3] = __builtin_amdgcn_mfma_f32_16x16x32_bf16(af2, bg3, acc[6][3], 0, 0, 0);
        acc[7][0] = __builtin_amdgcn_mfma_f32_16x16x32_bf16(af3, bg0, acc[7][0], 0, 0, 0);
        acc[7][1] = __builtin_amdgcn_mfma_f32_16x16x32_bf16(af3, bg1, acc[7][1], 0, 0, 0);
        acc[7][2] = __builtin_amdgcn_mfma_f32_16x16x32_bf16(af3, bg2, acc[7][2], 0, 0, 0);
        acc[7][3] = __builtin_amdgcn_mfma_f32_16x16x32_bf16(af3, bg3, acc[7][3], 0, 0, 0);
        __builtin_amdgcn_s_setprio(0);
        // counted vmcnt: tile j+1 landed; tile j+2's 4 loads stay in flight
        if (j + 2 < NT) {
            asm volatile("s_waitcnt vmcnt(4)" ::: "memory");
        } else if (j + 1 < NT) {
            asm volatile("s_waitcnt vmcnt(0)" ::: "memory");
        }
        __builtin_amdgcn_s_barrier();
    }

    // epilogue
    const int rb = (lane >> 4) * 4;
    const int cl = lane & 15;
#pragma unroll
    for (int mi = 0; mi < 8; ++mi)
#pragma unroll
        for (int rr = 0; rr < 4; ++rr) {
            long m = m0 + wm * 128 + mi * 16 + rb + rr;
#pragma unroll
            for (int ni = 0; ni < 4; ++ni)
                epi_store<MODE>(m, n0 + wn * 64 + ni * 16 + cl, acc[mi][ni][rr], bias, nullptr, ob, of);
        }
}

// ---------------------------------------------------------------- attention: one block per (b,h), 4 waves
__global__ __launch_bounds__(256, 2) void attn_kernel(
    const u16* __restrict__ qb, const u16* __restrict__ kb, const u16* __restrict__ vb,
    u16* __restrict__ aout) {
    __shared__ __align__(16) u16 Vt[64 * 232];        // V transposed [d][token], padded
    __shared__ __align__(16) u16 P[4][16 * 232];      // per-wave P tile
    const int bid = blockIdx.x;
    const int b = bid / NH;
    const int h = bid - b * NH;
    const int f = b & 7;
    int fs = (h < 2) ? (f > 0 ? f - 1 : 0) : ((h < 4) ? (f < 7 ? f + 1 : 7) : f);
    const int bsrc = (b & ~7) + fs;
    const u16* Qp = qb + (long)(b    * NH + h) * SEQ * HD;
    const u16* Kp = kb + (long)(bsrc * NH + h) * SEQ * HD;
    const u16* Vp = vb + (long)(bsrc * NH + h) * SEQ * HD;

    const int tid  = threadIdx.x;
    const int lane = tid & 63;
    const int w    = tid >> 6;
    const int cl   = lane & 15;
    const int lg   = lane >> 4;

    {   // zero Vt and P (pad columns must be exactly 0)
        unsigned int* z1 = (unsigned int*)Vt;
        for (int i = tid; i < 64 * 232 / 2; i += 256) z1[i] = 0;
        unsigned int* z2 = (unsigned int*)&P[0][0];
        for (int i = tid; i < 4 * 16 * 232 / 2; i += 256) z2[i] = 0;
    }
    __syncthreads();
    for (int g = tid; g < SEQ * HD / 8; g += 256) {   // transpose-stage V
        int t  = g >> 3;
        int d0 = (g & 7) * 8;
        u16x8 v = *(const u16x8*)(Vp + g * 8);
#pragma unroll
        for (int j = 0; j < 8; ++j) Vt[(d0 + j) * 232 + t] = v[j];
    }
    __syncthreads();

    const f32x4 vzero = {0.f, 0.f, 0.f, 0.f};
    u16* Pw = &P[w][0];
    for (int rt = w; rt < 13; rt += 4) {
        int qrow = rt * 16 + cl; if (qrow > SEQ - 1) qrow = SEQ - 1;
        bf16x8 qf0 = *(const bf16x8*)(Qp + qrow * HD + lg * 8);
        bf16x8 qf1 = *(const bf16x8*)(Qp + qrow * HD + 32 + lg * 8);
        f32x4 s[13];
#pragma unroll
        for (int ct = 0; ct < 13; ++ct) s[ct] = vzero;
#pragma unroll
        for (int ct = 0; ct < 13; ++ct) {
            int krow = ct * 16 + cl; if (krow > SEQ - 1) krow = SEQ - 1;
            bf16x8 kf0 = *(const bf16x8*)(Kp + krow * HD + lg * 8);
            bf16x8 kf1 = *(const bf16x8*)(Kp + krow * HD + 32 + lg * 8);
            s[ct] = __builtin_amdgcn_mfma_f32_16x16x32_bf16(qf0, kf0, s[ct], 0, 0, 0);
            s[ct] = __builtin_amdgcn_mfma_f32_16x16x32_bf16(qf1, kf1, s[ct], 0, 0, 0);
        }
        float rm[4] = {-1e30f, -1e30f, -1e30f, -1e30f};
#pragma unroll
        for (int ct = 0; ct < 13; ++ct) {
            bool valid = (ct * 16 + cl) <= SEQ - 1;
#pragma unroll
            for (int r = 0; r < 4; ++r) {
                float v = valid ? s[ct][r] * 0.125f : -1e30f;
                s[ct][r] = v;
                rm[r] = fmaxf(rm[r], v);
            }
        }
#pragma unroll
        for (int off = 1; off <= 8; off <<= 1)
#pragma unroll
            for (int r = 0; r < 4; ++r) rm[r] = fmaxf(rm[r], __shfl_xor(rm[r], off));
        float rs[4] = {0.f, 0.f, 0.f, 0.f};
#pragma unroll
        for (int ct = 0; ct < 13; ++ct)
#pragma unroll
            for (int r = 0; r < 4; ++r) {
                float p = __expf(s[ct][r] - rm[r]);
                s[ct][r] = p;
                rs[r] += p;
            }
#pragma unroll
        for (int off = 1; off <= 8; off <<= 1)
#pragma unroll
            for (int r = 0; r < 4; ++r) rs[r] += __shfl_xor(rs[r], off);
        float inv[4];
#pragma unroll
        for (int r = 0; r < 4; ++r) inv[r] = 1.f / rs[r];

        asm volatile("s_waitcnt lgkmcnt(0)" ::: "memory");
#pragma unroll
        for (int ct = 0; ct < 13; ++ct)
#pragma unroll
            for (int r = 0; r < 4; ++r)
                Pw[(lg * 4 + r) * 232 + ct * 16 + cl] = f2b(s[ct][r] * inv[r]);
        asm volatile("s_waitcnt lgkmcnt(0)" ::: "memory");

        bf16x8 pf[7];
#pragma unroll
        for (int ks = 0; ks < 7; ++ks)
            pf[ks] = *(const bf16x8*)(Pw + cl * 232 + ks * 32 + lg * 8);
#pragma unroll
        for (int dt = 0; dt < 4; ++dt) {
            f32x4 o = vzero;
#pragma unroll
            for (int ks = 0; ks < 7; ++ks) {
                bf16x8 vf = *(const bf16x8*)(&Vt[(dt * 16 + cl) * 232 + ks * 32 + lg * 8]);
                o = __builtin_amdgcn_mfma_f32_16x16x32_bf16(pf[ks], vf, o, 0, 0, 0);
            }
#pragma unroll
            for (int r = 0; r < 4; ++r) {
                int m = rt * 16 + lg * 4 + r;
                if (m < SEQ)
                    aout[(long)(b * SEQ + m) * CDIM + h * HD + dt * 16 + cl] = f2b(o[r]);
            }
        }
    }
}

// ---------------------------------------------------------------- launcher
extern "C" void kernel_launch(void* const* d_in, const int* in_sizes, int n_in,
                              void* d_out, int out_size, void* d_ws, size_t ws_size,
                              hipStream_t stream) {
    const float* x      = (const float*)d_in[0];
    const float* a_w1   = (const float*)d_in[1];
    const float* a_b1   = (const float*)d_in[2];
    const float* a_w2   = (const float*)d_in[3];
    const float* a_b2   = (const float*)d_in[4];
    const float* qkv_w  = (const float*)d_in[5];
    const float* qkv_b  = (const float*)d_in[6];
    const float* proj_w = (const float*)d_in[7];
    const float* proj_b = (const float*)d_in[8];
    float* out = (float*)d_out;
    char* ws = (char*)d_ws;

    // ws layout (bytes, 16B-aligned). MPAD = 12800 rows. Peak ~104.4 MiB.
    // aout ALIASES xb: xb dead after gemm_a1; attn writes valid rows; xb's
    // zero pad rows (12608..12799) double as aout's pad rows for gemm_proj.
    u16* xb   = (u16*)(ws + 0);          // [12800][768]  bf16
    u16* xa   = (u16*)(ws + 19660800);   // [12800][768]  bf16
    u16* hbuf = (u16*)(ws + 39321600);   // [12800][256]  bf16
    u16* w1t  = (u16*)(ws + 45875200);   // [256][768]    bf16
    u16* w2t  = (u16*)(ws + 46268416);   // [768][256]    bf16
    u16* qwt  = (u16*)(ws + 46661632);   // [2304][768]   bf16
    u16* pwt  = (u16*)(ws + 50200576);   // [768][768]    bf16
    u16* qkv  = (u16*)(ws + 51380224);   // [3][64][12][197][64] bf16
    u16* aout = xb;                      // alias (see above)

    cast_x_kernel<<<4800, 256, 0, stream>>>(x, xb);
    transpose_cast_kernel<<<dim3(12, 4),  256, 0, stream>>>(a_w1,   w1t, 768, 192,  768);
    transpose_cast_kernel<<<dim3(4, 12),  256, 0, stream>>>(a_w2,   w2t, 192, 768,  256);
    transpose_cast_kernel<<<dim3(12, 36), 256, 0, stream>>>(qkv_w,  qwt, 768, 2304, 768);
    transpose_cast_kernel<<<dim3(12, 12), 256, 0, stream>>>(proj_w, pwt, 768, 768,  768);

    gemm_a1<<<100 * 2, 256, 0, stream>>>(xb,   w1t, a_b1, hbuf, 768);
    gemm_a2<<<100 * 6, 256, 0, stream>>>(hbuf, w2t, a_b2, x, xa, 256);
    gemm8p<2, 9, 24><<<50 * 9, 512, 0, stream>>>(xa, qwt, qkv_b, qkv, nullptr, 768);
    attn_kernel<<<NBT * NH, 256, 0, stream>>>(qkv, qkv + QKVSZ, qkv + 2 * (long)QKVSZ, aout);
    gemm8p<3, 3, 24><<<50 * 3, 512, 0, stream>>>(aout, pwt, proj_b, nullptr, out, 768);
}